// Round 1
// 912.741 us; speedup vs baseline: 1.0172x; 1.0172x over previous
//
#include <hip/hip_runtime.h>
#include <math.h>

#define U_DIM 8001
#define I_DIM 16001
#define B_DIM 8192
#define BTILE 64          // b's per dot3 block
#define RC    128         // r-chunk staged in LDS (32 KB f32 tile -> 4 blocks/CU)
#define NYSPLIT 16        // r-splits for parallelism: grid = 128 x 16 = 2048 blocks

typedef float f32x4 __attribute__((ext_vector_type(4)));

__device__ __forceinline__ unsigned short f32_to_bf16_rne(float f) {
    union { float f; unsigned int u; } v; v.f = f;
    unsigned int r = v.u + 0x7fffu + ((v.u >> 16) & 1u);   // round-nearest-even
    return (unsigned short)(r >> 16);
}
__device__ __forceinline__ float bf16_to_f32(unsigned short h) {
    union { unsigned int u; float f; } v; v.u = ((unsigned int)h) << 16;
    return v.f;
}

// ---------------------------------------------------------------------------
// Phase 1: one block per row u. Stage row into LDS (coalesced, R read once,
// nontemporal so S/L2 stay clean), compute nonzero-mean ub inline, write
// gathered adjusted row as bf16 with nontemporal stores (u-major Ag).
// ---------------------------------------------------------------------------
__global__ __launch_bounds__(1024)
void gather_kernel(const float* __restrict__ R, const int* __restrict__ item,
                   unsigned short* __restrict__ Ag, int row0) {
    __shared__ float rowbuf[I_DIM];   // 64004 B
    __shared__ float red_s[16];
    __shared__ int   red_c[16];

    const int u   = row0 + blockIdx.x;
    const int tid = threadIdx.x;
    const float* rp = R + (size_t)u * I_DIM;

    float s = 0.f; int c = 0;
    const int pre  = (4 - (u & 3)) & 3;           // row align phase = u mod 4
    const int nvec = (I_DIM - pre) >> 2;
    const int vend = pre + (nvec << 2);

    for (int i = tid; i < pre; i += 1024) {
        float v = rp[i]; rowbuf[i] = v; s += v; c += (v != 0.f);
    }
    const f32x4* rv = (const f32x4*)(rp + pre);
    for (int i = tid; i < nvec; i += 1024) {
        f32x4 v = __builtin_nontemporal_load(rv + i);   // read-once: bypass L2
        const int base = pre + (i << 2);
        rowbuf[base    ] = v[0];
        rowbuf[base + 1] = v[1];
        rowbuf[base + 2] = v[2];
        rowbuf[base + 3] = v[3];
        s += v[0] + v[1] + v[2] + v[3];
        c += (v[0] != 0.f) + (v[1] != 0.f) + (v[2] != 0.f) + (v[3] != 0.f);
    }
    for (int i = vend + tid; i < I_DIM; i += 1024) {
        float v = rp[i]; rowbuf[i] = v; s += v; c += (v != 0.f);
    }

    #pragma unroll
    for (int off = 32; off > 0; off >>= 1) {
        s += __shfl_down(s, off, 64);
        c += __shfl_down(c, off, 64);
    }
    const int wid  = tid >> 6;
    const int lane = tid & 63;
    if (lane == 0) { red_s[wid] = s; red_c[wid] = c; }
    __syncthreads();

    float Sr = 0.f; int Cr = 0;
    #pragma unroll
    for (int k = 0; k < 16; ++k) { Sr += red_s[k]; Cr += red_c[k]; }
    const float ub = (Cr > 0) ? Sr / (float)Cr : 0.f;

    unsigned short* arow = Ag + (size_t)blockIdx.x * B_DIM;
    for (int b = tid; b < B_DIM; b += 1024) {
        float ad = rowbuf[item[b]] - ub;          // LDS gather
        __builtin_nontemporal_store(f32_to_bf16_rne(ad), &arow[b]);
    }
}

// ---------------------------------------------------------------------------
// Phase 2 (NEW): block owns 64 b's. Stage S[user[b0..b0+63]][r-chunk] into a
// XOR-swizzled [64][128] f32 LDS tile with fully coalesced dword loads
// (S rows are only 4B-aligned: stride 8001*4), then each lane dots its own
// LDS row against the coalesced nontemporal Ag column block.
//   write bank = read bank = (idx ^ (row&31)) & 31  -> 2 lanes/bank (free).
// Zero uncoalesced vector-memory ops; 32 KB LDS -> 4 blocks/CU.
// ---------------------------------------------------------------------------
__global__ __launch_bounds__(256)
void dot3_kernel(const float* __restrict__ S, const int* __restrict__ user,
                 const unsigned short* __restrict__ Ag, float* __restrict__ accum,
                 int row0, int nrows) {
    __shared__ float s_lds[BTILE][RC];
    __shared__ int   usr_s[BTILE];

    const int tid  = threadIdx.x;
    const int lane = tid & 63;
    const int w    = tid >> 6;             // wave 0..3
    const int b0   = blockIdx.x * BTILE;

    const int rpy = (nrows + NYSPLIT - 1) / NYSPLIT;
    const int rlo = blockIdx.y * rpy;
    const int rhi = min(nrows, rlo + rpy);

    if (tid < BTILE) usr_s[tid] = user[b0 + tid];
    __syncthreads();

    float acc = 0.f;
    const unsigned short* agb = Ag + b0 + lane;
    const int sw = lane & 31;

    for (int r0 = rlo; r0 < rhi; r0 += RC) {
        const int rc = min(RC, rhi - r0);

        // stage: wave w stages rows 16w..16w+15, coalesced dword per row
        #pragma unroll
        for (int k = 0; k < 16; ++k) {
            const int row = (w << 4) + k;
            const float* sp = S + (size_t)usr_s[row] * U_DIM + row0 + r0;
            for (int i = lane; i < rc; i += 64)
                s_lds[row][i ^ (row & 31)] = sp[i];
        }
        __syncthreads();

        // compute: lane owns b0+lane; wave w covers rr = w, w+4, ...
        const unsigned short* agp = agb + (size_t)r0 * B_DIM;
        #pragma unroll 8
        for (int rr = w; rr < rc; rr += 4) {
            unsigned short h = __builtin_nontemporal_load(agp + (size_t)rr * B_DIM);
            acc += s_lds[lane][rr ^ sw] * bf16_to_f32(h);
        }
        __syncthreads();
    }

    atomicAdd(&accum[b0 + lane], acc);     // 64 adds/entry total (4 waves x 16 y)
}

// ---------------------------------------------------------------------------
__global__ void finish_kernel(const float* __restrict__ accum,
                              const int* __restrict__ user,
                              const int* __restrict__ item,
                              const float* __restrict__ ubias,
                              const float* __restrict__ ibias,
                              const float* __restrict__ gb,
                              float* __restrict__ out) {
    const int b = blockIdx.x * blockDim.x + threadIdx.x;
    if (b < B_DIM) {
        float pred = accum[b] + ubias[user[b]] + ibias[item[b]] + gb[0];
        out[b] = 5.f / (1.f + expf(-pred));
    }
}

// ---------------------------------------------------------------------------
extern "C" void kernel_launch(void* const* d_in, const int* in_sizes, int n_in,
                              void* d_out, int out_size, void* d_ws, size_t ws_size,
                              hipStream_t stream) {
    const int*   user = (const int*)  d_in[0];
    const int*   item = (const int*)  d_in[1];
    const float* R    = (const float*)d_in[2];
    const float* S    = (const float*)d_in[3];
    const float* ubia = (const float*)d_in[4];
    const float* ibia = (const float*)d_in[5];
    const float* gb   = (const float*)d_in[6];
    float* out   = (float*)d_out;

    float*          accum = (float*)d_ws;                    // B_DIM f32
    unsigned short* Ag    = (unsigned short*)((char*)d_ws + (size_t)B_DIM * 4);

    size_t rg_bytes = (ws_size > (size_t)B_DIM * 4) ? ws_size - (size_t)B_DIM * 4 : 0;
    int max_rows = (int)(rg_bytes / ((size_t)B_DIM * 2));    // bf16 rows
    if (max_rows > U_DIM) max_rows = U_DIM;
    if (max_rows < 1)     max_rows = 1;

    hipMemsetAsync(accum, 0, B_DIM * sizeof(float), stream);

    for (int row0 = 0; row0 < U_DIM; row0 += max_rows) {
        const int nrows = min(max_rows, U_DIM - row0);
        gather_kernel<<<nrows, 1024, 0, stream>>>(R, item, Ag, row0);
        dot3_kernel<<<dim3(B_DIM / BTILE, NYSPLIT), 256, 0, stream>>>(
            S, user, Ag, accum, row0, nrows);
    }

    finish_kernel<<<(B_DIM + 255) / 256, 256, 0, stream>>>(accum, user, item,
                                                           ubia, ibia, gb, out);
}

// Round 2
// 911.659 us; speedup vs baseline: 1.0184x; 1.0012x over previous
//
#include <hip/hip_runtime.h>
#include <math.h>

#define U_DIM 8001
#define I_DIM 16001
#define B_DIM 8192
#define BTILE 64          // b's per dot3 block
#define RC    128         // r-chunk staged in LDS (32 KB f32 tile -> 4 blocks/CU)
#define NYSPLIT 16        // r-splits: grid = 128 x 16 = 2048 blocks (2 full CU rounds)

typedef float f32x4 __attribute__((ext_vector_type(4)));
typedef unsigned short u16x8 __attribute__((ext_vector_type(8)));

__device__ __forceinline__ unsigned short f32_to_bf16_rne(float f) {
    union { float f; unsigned int u; } v; v.f = f;
    unsigned int r = v.u + 0x7fffu + ((v.u >> 16) & 1u);   // round-nearest-even
    return (unsigned short)(r >> 16);
}
__device__ __forceinline__ float bf16_to_f32(unsigned short h) {
    union { unsigned int u; float f; } v; v.u = ((unsigned int)h) << 16;
    return v.f;
}

// ---------------------------------------------------------------------------
// Phase 1 (v2): one block per row u.
//  - LDS index map i -> i + sh, sh = (4 - pre) & 3: makes every staging write a
//    16B-ALIGNED ds_write_b128 (old code: 75% of rows hit 8-way write conflicts
//    via 4x ds_write_b32 at 4-elem lane stride).
//  - Ag stores packed: 8 bf16 -> one 16B nontemporal store per thread (8x fewer
//    store instructions; old: 2B/lane wave stores).
//  - item[] read as int4 pairs (cached; shared by all 8001 blocks).
// ---------------------------------------------------------------------------
__global__ __launch_bounds__(1024)
void gather_kernel(const float* __restrict__ R, const int* __restrict__ item,
                   unsigned short* __restrict__ Ag, int row0) {
    __shared__ __align__(16) float rowbuf[I_DIM + 4];   // +4: shift headroom
    __shared__ float red_s[16];
    __shared__ int   red_c[16];

    const int u   = row0 + blockIdx.x;
    const int tid = threadIdx.x;
    const float* rp = R + (size_t)u * I_DIM;

    const int pre = (4 - (u & 3)) & 3;   // elems before first 16B boundary of row
    const int sh  = (4 - pre) & 3;       // LDS shift so (pre+sh) % 4 == 0

    float s = 0.f; int c = 0;

    for (int i = tid; i < pre; i += 1024) {             // <=3 elems
        float v = rp[i]; rowbuf[i + sh] = v; s += v; c += (v != 0.f);
    }

    const int nvec = (I_DIM - pre) >> 2;
    const int vend = pre + (nvec << 2);
    const f32x4* rv = (const f32x4*)(rp + pre);         // 16B-aligned global
    f32x4*       lv = (f32x4*)(rowbuf + pre + sh);      // 16B-aligned LDS
    for (int i = tid; i < nvec; i += 1024) {
        f32x4 v = __builtin_nontemporal_load(rv + i);   // read-once: bypass L2
        lv[i] = v;                                      // ds_write_b128, conflict-free
        s += v[0] + v[1] + v[2] + v[3];
        c += (v[0] != 0.f) + (v[1] != 0.f) + (v[2] != 0.f) + (v[3] != 0.f);
    }
    for (int i = vend + tid; i < I_DIM; i += 1024) {    // <=3 elems
        float v = rp[i]; rowbuf[i + sh] = v; s += v; c += (v != 0.f);
    }

    #pragma unroll
    for (int off = 32; off > 0; off >>= 1) {
        s += __shfl_down(s, off, 64);
        c += __shfl_down(c, off, 64);
    }
    const int wid  = tid >> 6;
    const int lane = tid & 63;
    if (lane == 0) { red_s[wid] = s; red_c[wid] = c; }
    __syncthreads();                                    // covers rowbuf + red_*

    float Sr = 0.f; int Cr = 0;
    #pragma unroll
    for (int k = 0; k < 16; ++k) { Sr += red_s[k]; Cr += red_c[k]; }
    const float ub = (Cr > 0) ? Sr / (float)Cr : 0.f;

    // 1024 threads x 8 b's = 8192: exactly one packed 16B NT store each.
    const int4 ia = ((const int4*)item)[tid << 1];
    const int4 ib = ((const int4*)item)[(tid << 1) + 1];
    union { u16x8 v; unsigned short h[8]; } o;
    o.h[0] = f32_to_bf16_rne(rowbuf[ia.x + sh] - ub);
    o.h[1] = f32_to_bf16_rne(rowbuf[ia.y + sh] - ub);
    o.h[2] = f32_to_bf16_rne(rowbuf[ia.z + sh] - ub);
    o.h[3] = f32_to_bf16_rne(rowbuf[ia.w + sh] - ub);
    o.h[4] = f32_to_bf16_rne(rowbuf[ib.x + sh] - ub);
    o.h[5] = f32_to_bf16_rne(rowbuf[ib.y + sh] - ub);
    o.h[6] = f32_to_bf16_rne(rowbuf[ib.z + sh] - ub);
    o.h[7] = f32_to_bf16_rne(rowbuf[ib.w + sh] - ub);
    u16x8* arow = (u16x8*)(Ag + (size_t)blockIdx.x * B_DIM);
    __builtin_nontemporal_store(o.v, arow + tid);
}

// ---------------------------------------------------------------------------
// Phase 2: block owns 64 b's. Stage S[user[b0..b0+63]][r-chunk] into a
// XOR-swizzled [64][128] f32 LDS tile with fully coalesced dword loads
// (S rows are only 4B-aligned: stride 8001*4), then each lane dots its own
// LDS row against the coalesced nontemporal Ag column block.
//   bank = (idx ^ (row&31)) & 31 -> 2 lanes/bank (free, m136).
// ---------------------------------------------------------------------------
__global__ __launch_bounds__(256)
void dot3_kernel(const float* __restrict__ S, const int* __restrict__ user,
                 const unsigned short* __restrict__ Ag, float* __restrict__ accum,
                 int row0, int nrows) {
    __shared__ float s_lds[BTILE][RC];
    __shared__ int   usr_s[BTILE];

    const int tid  = threadIdx.x;
    const int lane = tid & 63;
    const int w    = tid >> 6;             // wave 0..3
    const int b0   = blockIdx.x * BTILE;

    const int rpy = (nrows + NYSPLIT - 1) / NYSPLIT;
    const int rlo = blockIdx.y * rpy;
    const int rhi = min(nrows, rlo + rpy);

    if (tid < BTILE) usr_s[tid] = user[b0 + tid];
    __syncthreads();

    float acc = 0.f;
    const unsigned short* agb = Ag + b0 + lane;
    const int sw = lane & 31;

    for (int r0 = rlo; r0 < rhi; r0 += RC) {
        const int rc = min(RC, rhi - r0);

        // stage: wave w stages rows 16w..16w+15, coalesced dword per row
        #pragma unroll
        for (int k = 0; k < 16; ++k) {
            const int row = (w << 4) + k;
            const float* sp = S + (size_t)usr_s[row] * U_DIM + row0 + r0;
            for (int i = lane; i < rc; i += 64)
                s_lds[row][i ^ (row & 31)] = sp[i];
        }
        __syncthreads();

        // compute: lane owns b0+lane; wave w covers rr = w, w+4, ...
        const unsigned short* agp = agb + (size_t)r0 * B_DIM;
        #pragma unroll 8
        for (int rr = w; rr < rc; rr += 4) {
            unsigned short h = __builtin_nontemporal_load(agp + (size_t)rr * B_DIM);
            acc += s_lds[lane][rr ^ sw] * bf16_to_f32(h);
        }
        __syncthreads();
    }

    atomicAdd(&accum[b0 + lane], acc);     // 64 adds/entry total (4 waves x 16 y)
}

// ---------------------------------------------------------------------------
__global__ void finish_kernel(const float* __restrict__ accum,
                              const int* __restrict__ user,
                              const int* __restrict__ item,
                              const float* __restrict__ ubias,
                              const float* __restrict__ ibias,
                              const float* __restrict__ gb,
                              float* __restrict__ out) {
    const int b = blockIdx.x * blockDim.x + threadIdx.x;
    if (b < B_DIM) {
        float pred = accum[b] + ubias[user[b]] + ibias[item[b]] + gb[0];
        out[b] = 5.f / (1.f + expf(-pred));
    }
}

// ---------------------------------------------------------------------------
extern "C" void kernel_launch(void* const* d_in, const int* in_sizes, int n_in,
                              void* d_out, int out_size, void* d_ws, size_t ws_size,
                              hipStream_t stream) {
    const int*   user = (const int*)  d_in[0];
    const int*   item = (const int*)  d_in[1];
    const float* R    = (const float*)d_in[2];
    const float* S    = (const float*)d_in[3];
    const float* ubia = (const float*)d_in[4];
    const float* ibia = (const float*)d_in[5];
    const float* gb   = (const float*)d_in[6];
    float* out   = (float*)d_out;

    float*          accum = (float*)d_ws;                    // B_DIM f32
    unsigned short* Ag    = (unsigned short*)((char*)d_ws + (size_t)B_DIM * 4);

    size_t rg_bytes = (ws_size > (size_t)B_DIM * 4) ? ws_size - (size_t)B_DIM * 4 : 0;
    int max_rows = (int)(rg_bytes / ((size_t)B_DIM * 2));    // bf16 rows
    if (max_rows > U_DIM) max_rows = U_DIM;
    if (max_rows < 1)     max_rows = 1;

    hipMemsetAsync(accum, 0, B_DIM * sizeof(float), stream);

    for (int row0 = 0; row0 < U_DIM; row0 += max_rows) {
        const int nrows = min(max_rows, U_DIM - row0);
        gather_kernel<<<nrows, 1024, 0, stream>>>(R, item, Ag, row0);
        dot3_kernel<<<dim3(B_DIM / BTILE, NYSPLIT), 256, 0, stream>>>(
            S, user, Ag, accum, row0, nrows);
    }

    finish_kernel<<<(B_DIM + 255) / 256, 256, 0, stream>>>(accum, user, item,
                                                           ubia, ibia, gb, out);
}